// Round 3
// baseline (784.679 us; speedup 1.0000x reference)
//
#include <hip/hip_runtime.h>
#include <stdint.h>

// TGN recommender fused pipeline — fp16 MFMA variant.
#define BATCH   262144
#define DMEM    100       // memory dim
#define ROWS    32        // rows per block (v4: halved for 4 blocks/CU)
#define AS      456       // LDS A row stride (elements): 448 used + 8 pad

typedef float    f32x4 __attribute__((ext_vector_type(4)));
typedef _Float16 f16x8 __attribute__((ext_vector_type(8)));
typedef unsigned short u16x4 __attribute__((ext_vector_type(4)));

__device__ __forceinline__ unsigned short f2h(float f) {
  union { _Float16 h; unsigned short u; } v; v.h = (_Float16)f;  // RNE
  return v.u;
}
__device__ __forceinline__ float h2f(unsigned short u) {
  union { _Float16 h; unsigned short u; } v; v.u = u; return (float)v.h;
}

#define MFMA16(A, B, C) __builtin_amdgcn_mfma_f32_16x16x32_f16((A), (B), (C), 0, 0, 0)

// ---------------------------------------------------------------------------
// Per-wave nt (output column tile) partition for the main GEMM.
// Op counts per nt: nt 0..12 -> 14 ops (kc 0..13); nt 13..18 -> 10 (kc 0..9);
// nt 19..25 -> 4 (kc 10..13). Partition balances to 68/68/66/68 ops per wave
// and dedups B reads (each fragment read ONCE per block).
// ---------------------------------------------------------------------------
namespace wcfg {
constexpr int NT[4][7] = {
  {0, 1, 2, 3, 19, 20, 21},
  {4, 5, 6, 7, 22, 23, 24},
  {8, 9, 10, 11, 13, 13, 13},   // padding repeats guarded by LEN
  {12, 14, 15, 16, 17, 18, 25}};
constexpr int LEN[4] = {7, 7, 5, 7};
}

// ---------------------------------------------------------------------------
// Prep: pack weights into MFMA B-operand fragment order (fp16).
// Main GEMM op list (270 ops), A columns: [0:304)=x (src|dst|msg|t_enc),
// [304:320)=0, [320:420)=h, [420:448)=0.
//   phase1: kc 0..9  (K 0:320),  nt 0..18 (cols 0:304)  -> W_ih[col][k]
//   phase2: kc 10..13 (K 320:448), nt 0..12 (cols 0:208) -> W_hh[col][k-320], col<200
//   phase3: kc 10..13,            nt 19..25 (cols 304:416)-> W_hh[200+(col-304)][k-320]
// op index: o<190: kc=o/19, nt=o%19 ; else o2=o-190: kc=10+o2/20, p=o2%20,
//           nt = p<13 ? p : p+6.
// W1 ops (16): kc 0..3 (K=128 over h_new), nt 0..3 (64 cols).
// B-fragment layout for v_mfma_f32_16x16x32_f16: lane holds B[k][n],
// n=lane&15, k=(lane>>4)*8+j  -> frag[o][lane][j].
// Also zeroes stats_g (replaces the hipMemsetAsync dispatch).
// ---------------------------------------------------------------------------
__global__ void prep_kernel(const float* __restrict__ W_ih, const float* __restrict__ W_hh,
                            const float* __restrict__ W1,
                            const float* __restrict__ b_ih, const float* __restrict__ b_hh,
                            unsigned short* __restrict__ Bfrag,
                            unsigned short* __restrict__ W1frag,
                            float* __restrict__ biasbuf,
                            float* __restrict__ stats_g) {
  int blk = blockIdx.x;
  int tid = threadIdx.x;
  if (blk == 72) {                       // fused biases + stats zero
    if (tid < 128) stats_g[tid] = 0.f;
    if (tid < 100) {
      biasbuf[tid]       = b_ih[tid]       + b_hh[tid];        // r
      biasbuf[100 + tid] = b_ih[100 + tid] + b_hh[100 + tid];  // z
      biasbuf[200 + tid] = b_ih[200 + tid];                    // i_n
      biasbuf[300 + tid] = b_hh[200 + tid];                    // h_n
    }
    return;
  }
  int o = blk * 4 + (tid >> 6);
  if (o >= 286) return;
  int lane = tid & 63, quad = lane >> 4, l15 = lane & 15;
  if (o < 270) {
    int kc, nt;
    if (o < 190) { kc = o / 19; nt = o % 19; }
    else { int o2 = o - 190; kc = 10 + o2 / 20; int p = o2 % 20; nt = (p < 13) ? p : p + 6; }
    int col = nt * 16 + l15;
    unsigned short* dst = Bfrag + (size_t)o * 512 + lane * 8;
    for (int j = 0; j < 8; ++j) {
      int kg = kc * 32 + quad * 8 + j;
      float v = 0.f;
      if (kc < 10) {
        if (kg < 304 && col < 300) v = W_ih[col * 304 + kg];
      } else {
        int kl = kg - 320;
        if (nt < 13) { if (kl < 100 && col < 200) v = W_hh[col * 100 + kl]; }
        else { int hd = col - 304; if (kl < 100 && hd < 100) v = W_hh[(200 + hd) * 100 + kl]; }
      }
      dst[j] = f2h(v);
    }
  } else {
    int o1 = o - 270;
    int kc = o1 >> 2, nt = o1 & 3;
    int col = nt * 16 + l15;
    unsigned short* dst = W1frag + (size_t)o1 * 512 + lane * 8;
    for (int j = 0; j < 8; ++j) {
      int kg = kc * 32 + quad * 8 + j;
      dst[j] = f2h((kg < 100) ? W1[col * 100 + kg] : 0.f);
    }
  }
}

// ---------------------------------------------------------------------------
// GEMM core (templated on wave id so acc indexing stays compile-time).
// kc-outer; per kc: batch-issue this kc's owned B fragments (5-7 coalesced
// 16B/lane L2 loads), then 2 A ds_reads, then MFMAs. No explicit cross-kc
// double-buffer: at 16 waves/CU the TLP hides the L2 latency, and dropping
// the bn[] buffer keeps the wave under the 128-VGPR cap for 4 waves/SIMD.
// ---------------------------------------------------------------------------
template<int W>
__device__ __forceinline__ void gemm_core(f32x4 (&acc)[7][2],
    const unsigned short* __restrict__ Bfrag, const unsigned short* Arow,
    int quad, size_t boff) {
  constexpr auto& NT = wcfg::NT[W];
  constexpr int L = wcfg::LEN[W];
  #pragma unroll
  for (int kc = 0; kc < 14; ++kc) {
    const int kb = kc * 32 + quad * 8;
    f16x8 bq[7];
    #pragma unroll
    for (int t = 0; t < 7; ++t) {
      if (t >= L) continue;
      const bool member = (kc < 10) ? (NT[t] < 19) : (NT[t] < 13 || NT[t] >= 19);
      if (member) {
        const int op = (kc < 10) ? (kc * 19 + NT[t])
                     : (190 + (kc - 10) * 20 + ((NT[t] < 13) ? NT[t] : NT[t] - 6));
        bq[t] = *(const f16x8*)(Bfrag + (size_t)op * 512 + boff);
      }
    }
    f16x8 af0 = __builtin_bit_cast(f16x8, *(const uint4*)(Arow + kb));
    f16x8 af1 = __builtin_bit_cast(f16x8, *(const uint4*)(Arow + 16 * AS + kb));
    #pragma unroll
    for (int t = 0; t < 7; ++t) {
      if (t >= L) continue;
      const bool member = (kc < 10) ? (NT[t] < 19) : (NT[t] < 13 || NT[t] >= 19);
      if (member) {
        acc[t][0] = MFMA16(af0, bq[t], acc[t][0]);
        acc[t][1] = MFMA16(af1, bq[t], acc[t][1]);
      }
    }
  }
}

template<int W>
__device__ __forceinline__ void dump_acc(const f32x4 (&acc)[7][2],
    unsigned short* A_lds, int quad, int l15) {
  constexpr auto& NT = wcfg::NT[W];
  constexpr int L = wcfg::LEN[W];
  #pragma unroll
  for (int t = 0; t < 7; ++t)
    if (t < L) {
      const int col = NT[t] * 16 + l15;
      #pragma unroll
      for (int m = 0; m < 2; ++m) {
        const int rbase = m * 16 + quad * 4;
        #pragma unroll
        for (int rr = 0; rr < 4; ++rr)
          A_lds[(rbase + rr) * AS + col] = f2h(acc[t][m][rr]);
      }
    }
}

// ---------------------------------------------------------------------------
// Main fused kernel: 32 rows/block, 256 threads (4 waves), 8192 blocks.
// v4: LDS 37.5 KB -> 4 blocks/CU = 16 waves/CU (50% occupancy), double v3.
// The four resident blocks sit at staggered phases (gather-HBM / GEMM-L2 /
// gates-VALU / epilogue), so each pipe stays fed. Wave nt-partition and the
// barrier-free batched-B GEMM carry over; acc halves to [7][2].
// ---------------------------------------------------------------------------
__global__ __launch_bounds__(256, 4)
void main_kernel(const int* __restrict__ n_id, const float* __restrict__ memory,
                 const int* __restrict__ last_update,
                 const int* __restrict__ store_src, const int* __restrict__ store_dst,
                 const int* __restrict__ store_t, const float* __restrict__ store_msg,
                 const float* __restrict__ time_w, const float* __restrict__ time_b,
                 const float* __restrict__ b1,
                 const unsigned short* __restrict__ Bfrag,
                 const unsigned short* __restrict__ W1frag,
                 const float* __restrict__ biasbuf,
                 unsigned short* __restrict__ a_ws, float* __restrict__ stats_g) {
  __shared__ __align__(16) unsigned short A_lds[ROWS * AS];  // 29184 B
  __shared__ __align__(16) unsigned short hbuf[ROWS * 100];  // 6400 B
  __shared__ float bias_lds[400];                            // 1600 B
  __shared__ float stats[128];                               // 512 B

  const int tid  = threadIdx.x;
  const int wave = tid >> 6;
  const int lane = tid & 63;
  const int quad = lane >> 4;
  const int l15  = lane & 15;
  const int blk  = blockIdx.x;
  const size_t boff = (size_t)lane * 8;

  if (tid < 128) stats[tid] = 0.f;
  if (tid < 200) {                       // stage fused biases to LDS
    bias_lds[tid]       = biasbuf[tid];
    bias_lds[200 + tid] = biasbuf[200 + tid];
  }

  // ---- stage A tile: vectorized gathers + time encoding, fp16 into LDS ----
  {
    const int r = tid >> 3;           // row 0..31
    const int p = tid & 7;            // eighth 0..7
    const int b = blk * ROWS + r;
    const int n = n_id[b];
    const int sidx = store_src[n];
    const int didx = store_dst[n];
    const int stt  = store_t[n];
    const int lu   = last_update[n];
    const float* ms = memory + (size_t)sidx * DMEM;
    const float* md = memory + (size_t)didx * DMEM;
    const float* mh = memory + (size_t)n * DMEM;
    unsigned short* Ar = A_lds + r * AS;

    // 75 real float4 units per row (25 src + 25 dst + 25 h) over 8 threads
    // x 10 slots; v>=75 are dummies (re-load mh[0:4] -> pad col 448, benign
    // same-value race). All 10 loads issued before any conversion (deep MLP).
    f32x4 vals[10];
    #pragma unroll
    for (int i = 0; i < 10; ++i) {
      const int v = i * 8 + p;
      const int a = v / 25;
      const int c = v - a * 25;
      const float* bp = (a == 0) ? ms : ((a == 1) ? md : ((a == 2) ? mh : mh));
      vals[i] = (a < 3) ? *(const f32x4*)(bp + c * 4) : *(const f32x4*)mh;
    }
    f32x4 mg;
    if (p == 0) mg = *(const f32x4*)(store_msg + (size_t)n * 4);

    // t_enc (cols 204:304) computed WHILE gathers are in flight
    const float dtf = (float)(stt - lu);
    #pragma unroll
    for (int i = 0; i < 13; ++i) {
      const int d = p * 13 + i;
      if (d < 100)
        Ar[204 + d] = f2h(cosf(dtf * time_w[d] + time_b[d]));
    }
    if (p == 0) {                       // raw_msg (cols 200:204)
      u16x4 m4 = { f2h(mg[0]), f2h(mg[1]), f2h(mg[2]), f2h(mg[3]) };
      *(u16x4*)(Ar + 200) = m4;
    } else if (p == 1) {                // zero pad [304:320)
      uint4 z4 = {0u, 0u, 0u, 0u};
      *(uint4*)(Ar + 304) = z4;
      *(uint4*)(Ar + 312) = z4;
    } else if (p == 2) {                // zero pad [420:436)
      u16x4 z = {0, 0, 0, 0};
      *(u16x4*)(Ar + 420) = z; *(u16x4*)(Ar + 424) = z;
      *(u16x4*)(Ar + 428) = z; *(u16x4*)(Ar + 432) = z;
    } else if (p == 3) {                // zero pad [436:448)
      u16x4 z = {0, 0, 0, 0};
      *(u16x4*)(Ar + 436) = z; *(u16x4*)(Ar + 440) = z; *(u16x4*)(Ar + 444) = z;
    }
    // consume gathers (vmcnt waits land here, after the cos work)
    #pragma unroll
    for (int i = 0; i < 10; ++i) {
      const int v = i * 8 + p;
      const int a = v / 25;
      const int c = v - a * 25;
      const int off = (a == 0) ? (c * 4)
                    : ((a == 1) ? (100 + c * 4)
                    : ((a == 2) ? (320 + c * 4) : 448));
      u16x4 h4 = { f2h(vals[i][0]), f2h(vals[i][1]), f2h(vals[i][2]), f2h(vals[i][3]) };
      *(u16x4*)(Ar + off) = h4;       // 8B aligned (AS*2=912, off*2 %8==0)
    }
  }

  f32x4 acc[7][2];
  #pragma unroll
  for (int t = 0; t < 7; ++t)
    #pragma unroll
    for (int m = 0; m < 2; ++m) acc[t][m] = f32x4{0.f, 0.f, 0.f, 0.f};

  __syncthreads();                       // A fully staged

  const unsigned short* Arow = A_lds + l15 * AS;
  switch (wave) {
    case 0: gemm_core<0>(acc, Bfrag, Arow, quad, boff); break;
    case 1: gemm_core<1>(acc, Bfrag, Arow, quad, boff); break;
    case 2: gemm_core<2>(acc, Bfrag, Arow, quad, boff); break;
    default: gemm_core<3>(acc, Bfrag, Arow, quad, boff); break;
  }
  __syncthreads();                       // all A-fragment reads done

  // ---- copy h (A cols 320:420) into hbuf before the acc dump overwrites A ----
  #pragma unroll
  for (int i = 0; i < 13; ++i) {
    int e = tid + 256 * i;                             // 0..3327
    if (e < ROWS * 100)
      hbuf[e] = A_lds[(e / 100) * AS + 320 + (e % 100)];
  }
  __syncthreads();

  // ---- dump accumulators (pre-activation gates) to LDS as fp16 ----
  switch (wave) {
    case 0: dump_acc<0>(acc, A_lds, quad, l15); break;
    case 1: dump_acc<1>(acc, A_lds, quad, l15); break;
    case 2: dump_acc<2>(acc, A_lds, quad, l15); break;
    default: dump_acc<3>(acc, A_lds, quad, l15); break;
  }

  // W1 B fragments: issue now so the loads complete under the gates phase.
  f16x8 wb[4];
  #pragma unroll
  for (int k4 = 0; k4 < 4; ++k4)
    wb[k4] = *(const f16x8*)(W1frag + (size_t)(k4 * 4 + wave) * 512 + boff);

  __syncthreads();                       // dump visible

  // ---- GRU gates -> h_new (fp16, into cols 0:100) ----
  // NOTE: cols 100..127 are intentionally NOT zeroed for the W1 GEMM: W1frag
  // has exact 0.0 weights for kg>=100, so stale (finite) preacts contribute
  // 0*v = 0. A zeroing loop here would RACE with the Gr[100+d] reads of
  // slower waves in this same barrier epoch.
  #pragma unroll
  for (int i = 0; i < 13; ++i) {
    int e = tid + 256 * i;
    if (e < ROWS * 100) {
      int r = e / 100, d = e % 100;
      const unsigned short* Gr = A_lds + r * AS;
      float s_r = h2f(Gr[d])       + bias_lds[d];
      float s_z = h2f(Gr[100 + d]) + bias_lds[100 + d];
      float i_n = h2f(Gr[200 + d]) + bias_lds[200 + d];
      float h_n = h2f(Gr[304 + d]) + bias_lds[300 + d];
      float h   = h2f(hbuf[r * 100 + d]);
      float rg = __builtin_amdgcn_rcpf(1.f + __expf(-s_r));
      float zg = __builtin_amdgcn_rcpf(1.f + __expf(-s_z));
      float x2 = i_n + rg * h_n;
      x2 = fminf(fmaxf(x2, -30.f), 30.f);            // keep e2 finite
      float e2 = __expf(-2.f * x2);
      float nn = (1.f - e2) * __builtin_amdgcn_rcpf(1.f + e2);   // tanh(x2)
      float hw = (1.f - zg) * nn + zg * h;
      A_lds[r * AS + d] = f2h(hw);
    }
  }
  __syncthreads();

  // ---- a = relu(h_new @ W1^T + b1): K=128 (4 kc); wave w owns col tile w ----
  f32x4 aacc[2];
  #pragma unroll
  for (int m = 0; m < 2; ++m) aacc[m] = f32x4{0.f, 0.f, 0.f, 0.f};
  #pragma unroll
  for (int k4 = 0; k4 < 4; ++k4) {
    const int kb = k4 * 32 + quad * 8;
    #pragma unroll
    for (int m = 0; m < 2; ++m) {
      f16x8 a = __builtin_bit_cast(f16x8, *(const uint4*)(Arow + m * 16 * AS + kb));
      aacc[m] = MFMA16(a, wb[k4], aacc[m]);
    }
  }

  // ---- +b1, relu, BN partial stats, store a (fp16) ----
  const int col = wave * 16 + l15;
  const float bb = b1[col];
  float ssum = 0.f, ssq = 0.f;
  #pragma unroll
  for (int m = 0; m < 2; ++m) {
    const int rbase = m * 16 + quad * 4;
    #pragma unroll
    for (int rr = 0; rr < 4; ++rr) {
      float v = fmaxf(aacc[m][rr] + bb, 0.f);
      ssum += v; ssq += v * v;
      a_ws[(size_t)(blk * ROWS + rbase + rr) * 64 + col] = f2h(v);
    }
  }
  ssum += __shfl_xor(ssum, 16); ssum += __shfl_xor(ssum, 32);
  ssq  += __shfl_xor(ssq, 16);  ssq  += __shfl_xor(ssq, 32);
  if (quad == 0) {
    atomicAdd(&stats[col], ssum);
    atomicAdd(&stats[64 + col], ssq);
  }
  __syncthreads();
  if (tid < 128) atomicAdd(&stats_g[tid], stats[tid]);   // one atomic/channel/block
}

// ---------------------------------------------------------------------------
// Output: fold BN (mu, var, gamma, beta) + W2/b2 into out = a.w_c + C_c.
// ---------------------------------------------------------------------------
__global__ __launch_bounds__(256)
void out_kernel(const unsigned short* __restrict__ a_ws, const float* __restrict__ stats_g,
                const float* __restrict__ gamma, const float* __restrict__ beta,
                const float* __restrict__ W2, const float* __restrict__ b2,
                float* __restrict__ out) {
  __shared__ float w0[64], w1[64], cpart[128];
  __shared__ float C0s, C1s;
  int tid = threadIdx.x;
  if (tid < 64) {
    const float invB = 1.f / (float)BATCH;
    float mu  = stats_g[tid] * invB;
    float var = stats_g[64 + tid] * invB - mu * mu;
    float g   = gamma[tid] * rsqrtf(var + 1e-5f);
    w0[tid] = g * W2[tid];
    w1[tid] = g * W2[64 + tid];
    float t = beta[tid] - mu * g;
    cpart[tid]      = t * W2[tid];
    cpart[64 + tid] = t * W2[64 + tid];
  }
  __syncthreads();
  if (tid == 0) {
    float c0 = b2[0], c1 = b2[1];
    for (int j = 0; j < 64; ++j) { c0 += cpart[j]; c1 += cpart[64 + j]; }
    C0s = c0; C1s = c1;
  }
  __syncthreads();
  int b = blockIdx.x * 256 + tid;
  const uint4* ap = (const uint4*)(a_ws + (size_t)b * 64);
  float o0 = C0s, o1 = C1s;
  #pragma unroll
  for (int i = 0; i < 8; ++i) {
    uint4 v = ap[i];
    unsigned int uu[4] = {v.x, v.y, v.z, v.w};
    #pragma unroll
    for (int q = 0; q < 4; ++q) {
      float lo = h2f((unsigned short)(uu[q] & 0xffffu));
      float hi = h2f((unsigned short)(uu[q] >> 16));
      int j = i * 8 + q * 2;
      o0 += lo * w0[j] + hi * w0[j + 1];
      o1 += lo * w1[j] + hi * w1[j + 1];
    }
  }
  *(float2*)(out + (size_t)b * 2) = make_float2(o0, o1);
}

// ---------------------------------------------------------------------------
extern "C" void kernel_launch(void* const* d_in, const int* in_sizes, int n_in,
                              void* d_out, int out_size, void* d_ws, size_t ws_size,
                              hipStream_t stream) {
  const int*   n_id   = (const int*)d_in[0];
  const float* memory = (const float*)d_in[1];
  const int*   last_u = (const int*)d_in[2];
  const int*   s_src  = (const int*)d_in[3];
  const int*   s_dst  = (const int*)d_in[4];
  const int*   s_t    = (const int*)d_in[5];
  const float* s_msg  = (const float*)d_in[6];
  const float* time_w = (const float*)d_in[7];
  const float* time_b = (const float*)d_in[8];
  const float* W_ih   = (const float*)d_in[9];
  const float* b_ih   = (const float*)d_in[10];
  const float* W_hh   = (const float*)d_in[11];
  const float* b_hh   = (const float*)d_in[12];
  const float* W1     = (const float*)d_in[13];
  const float* b1     = (const float*)d_in[14];
  const float* gamma  = (const float*)d_in[15];
  const float* beta   = (const float*)d_in[16];
  const float* W2     = (const float*)d_in[17];
  const float* b2     = (const float*)d_in[18];

  char* ws = (char*)d_ws;
  float*          stats_g = (float*)ws;                                   // 512 B
  float*          biasbuf = (float*)(ws + 512);                           // 1600 B
  unsigned short* Bfrag   = (unsigned short*)(ws + 4096);                 // 270 KiB
  unsigned short* W1frag  = (unsigned short*)(ws + 4096 + 276480);        // 16 KiB
  unsigned short* a_ws    = (unsigned short*)(ws + (1u << 20));           // 32 MiB

  prep_kernel<<<73, 256, 0, stream>>>(W_ih, W_hh, W1, b_ih, b_hh, Bfrag, W1frag,
                                      biasbuf, stats_g);
  main_kernel<<<BATCH / ROWS, 256, 0, stream>>>(n_id, memory, last_u, s_src, s_dst, s_t,
                                                s_msg, time_w, time_b, b1,
                                                Bfrag, W1frag, biasbuf, a_ws, stats_g);
  out_kernel<<<1024, 256, 0, stream>>>(a_ws, stats_g, gamma, beta, W2, b2, (float*)d_out);
}